// Round 14
// baseline (1775.591 us; speedup 1.0000x reference)
//
#include <hip/hip_runtime.h>
#include <cstdint>

#define BB 16
#define NN 8192
#define MM 1024
#define KNN 32
#define CIN 64
#define HID 64
#define OCH 128

// workspace float offsets
#define KNN_OFF   0u          // 524288 ints
#define SUM1_OFF  524288u     // 2048
#define SUM2_OFF  526336u     // 4096
#define A1_OFF    530432u     // 1024
#define D1_OFF    531456u     // 1024
#define A2_OFF    532480u     // 2048
#define D2_OFF    534528u     // 2048
#define W2B_OFF   536576u     // 4096 floats = 8192 bf16 (w2 pre-converted)
#define Y1_OFF    540672u     // y1 now bf16: 33554432 elems = 64MB; pts4 aliases head
#define PTS4_OFF  Y1_OFF      // 131072 float4 (dead once conv1 runs)

typedef unsigned long long u64;
typedef float f32x4 __attribute__((ext_vector_type(4)));
typedef float f32x2 __attribute__((ext_vector_type(2)));
typedef short bf16x8 __attribute__((ext_vector_type(8)));

__device__ __forceinline__ unsigned short f2bf(float f) {
  union { float f; unsigned u; } v; v.f = f;
  unsigned r = v.u + 0x7FFFu + ((v.u >> 16) & 1u);   // RNE
  return (unsigned short)(r >> 16);
}
__device__ __forceinline__ float bf2f(unsigned short u) {
  return __uint_as_float(((unsigned)u) << 16);
}

// ---------------- K0: zero stats + packed (x,y,z,|x|^2) + w2 -> bf16 ----------
__global__ __launch_bounds__(256) void k0_init(const float* __restrict__ xyz,
                                               const float* __restrict__ w2,
                                               float* __restrict__ ws) {
  int t = blockIdx.x * 256 + threadIdx.x;
  if (t < 12288) ws[SUM1_OFF + t] = 0.0f;
  if (t < 4096) {   // w2: 128x64 f32 -> bf16 pairs (RNE, same as conv f2bf path)
    unsigned lo = f2bf(w2[2 * t]);
    unsigned hi = f2bf(w2[2 * t + 1]);
    ((unsigned*)(ws + W2B_OFF))[t] = lo | (hi << 16);
  }
  if (t < BB * NN) {
    #pragma clang fp contract(off)
    float x = xyz[(size_t)t * 3], y = xyz[(size_t)t * 3 + 1], z = xyz[(size_t)t * 3 + 2];
    ((float4*)(ws + PTS4_OFF))[t] = make_float4(x, y, z, (x * x + y * y) + z * z);
  }
}

// DPP u64 max-reduction across a wave; full max lands in lane 63.
__device__ __forceinline__ u64 wave_max_u64(u64 v) {
  #define DPP_RND(ctrl, rm)                                                     \
  {                                                                             \
    int lo_ = __builtin_amdgcn_update_dpp(0, (int)(unsigned)(v & 0xFFFFFFFFull),\
                                          ctrl, rm, 0xf, true);                 \
    int hi_ = __builtin_amdgcn_update_dpp(0, (int)(unsigned)(v >> 32),          \
                                          ctrl, rm, 0xf, true);                 \
    u64 o_ = ((u64)(unsigned)hi_ << 32) | (unsigned)lo_;                        \
    v = o_ > v ? o_ : v;                                                        \
  }
  DPP_RND(0x111, 0xf)  // row_shr:1
  DPP_RND(0x112, 0xf)  // row_shr:2
  DPP_RND(0x114, 0xf)  // row_shr:4
  DPP_RND(0x118, 0xf)  // row_shr:8
  DPP_RND(0x142, 0xa)  // row_bcast:15 -> rows 1,3
  DPP_RND(0x143, 0xc)  // row_bcast:31 -> rows 2,3
  #undef DPP_RND
  return v;
}

// ---------------- K1: FPS — 256 thr (4 waves, 1/SIMD), packed distance --------
// R13 post-mortem: distance-loop issue is a minority of the 2160 cyc/step;
// tail (barrier skew over 8 waves at 2/SIMD + 8 serialized atomics) dominates.
// 256 thr: same issue wall (4 waves on 4 SIMDs, no sharing), half the tail.
// Selection math bit-identical: packed IEEE per slot, ascending-index order.
__global__ __launch_bounds__(256) void fps_kernel(const float* __restrict__ xyz,
                                                  float* __restrict__ cent) {
  #pragma clang fp contract(off)
  __shared__ float4 sp4[NN];     // 128 KB
  __shared__ u64 slots[MM];      // 8 KB
  const int b = blockIdx.x, tid = threadIdx.x;
  const float* xp = xyz + (size_t)b * NN * 3;
  f32x2 px[16], py[16], pz[16];
  float dist0[16], dist1[16];
  #pragma unroll
  for (int i = 0; i < 16; ++i) {
    int n0 = tid + (2 * i) * 256, n1 = tid + (2 * i + 1) * 256;
    float x0 = xp[n0 * 3], y0 = xp[n0 * 3 + 1], z0 = xp[n0 * 3 + 2];
    float x1 = xp[n1 * 3], y1 = xp[n1 * 3 + 1], z1 = xp[n1 * 3 + 2];
    px[i] = (f32x2){x0, x1}; py[i] = (f32x2){y0, y1}; pz[i] = (f32x2){z0, z1};
    sp4[n0] = make_float4(x0, y0, z0, 0.0f);
    sp4[n1] = make_float4(x1, y1, z1, 0.0f);
    dist0[i] = 1e10f; dist1[i] = 1e10f;
  }
  for (int s = tid; s < MM; s += 256) slots[s] = 0ull;
  __syncthreads();
  int far = 0;
  float* co = cent + (size_t)b * MM * 3;
  for (int step = 0; step < MM; ++step) {
    float4 c4 = sp4[far];
    if (tid == 0) { co[step * 3] = c4.x; co[step * 3 + 1] = c4.y; co[step * 3 + 2] = c4.z; }
    f32x2 cx = (f32x2){c4.x, c4.x}, cy = (f32x2){c4.y, c4.y}, cz = (f32x2){c4.z, c4.z};
    float best = -1.0f; int bi = 0;
    #pragma unroll
    for (int i = 0; i < 16; ++i) {
      f32x2 dx = px[i] - cx, dy = py[i] - cy, dz = pz[i] - cz;
      f32x2 d = (dx * dx + dy * dy) + dz * dz;   // np: left-assoc, no fma (per slot)
      float dm0 = fminf(dist0[i], d.x);
      float dm1 = fminf(dist1[i], d.y);
      dist0[i] = dm0; dist1[i] = dm1;
      if (dm0 > best) { best = dm0; bi = tid + (2 * i) * 256; }      // strict >: lowest n
      if (dm1 > best) { best = dm1; bi = tid + (2 * i + 1) * 256; }
    }
    u64 key = ((u64)__float_as_uint(best) << 32) | (unsigned)(8191 - bi);
    key = wave_max_u64(key);
    if ((tid & 63) == 63) atomicMax(&slots[step], key);   // max dist, tie -> lowest idx
    __syncthreads();
    far = 8191 - (int)(unsigned)(slots[step] & 0xFFFFFFFFull);
  }
}

// ---------------- K2: kNN — 8-way N-split, bank-free buffers, tree merge ------
__global__ __launch_bounds__(512) void knn_kernel(const float4* __restrict__ pts4,
                                                  const float* __restrict__ cent,
                                                  int* __restrict__ knnout) {
  #pragma clang fp contract(off)
  __shared__ __align__(16) char smem[65536];
  unsigned* blo = (unsigned*)smem;              // [16][512] cand idx (bank-free)
  unsigned* bhi = (unsigned*)(smem + 32768);    // [16][512] cand key-hi
  u64* marea = (u64*)smem;                      // 4 areas x [32][64]; aliases buffers
                                                // AFTER the post-scan barrier (R5 lesson)
  const int tid = threadIdx.x;
  const int lane = tid & 63;
  const int w = tid >> 6;          // wave id = N-octant
  const int b = blockIdx.x >> 4;
  const int m = ((blockIdx.x & 15) << 6) + lane;
  const float* cp = cent + ((size_t)b * MM + m) * 3;
  float cx = cp[0], cy = cp[1], cz = cp[2];
  float cn2 = (cx * cx + cy * cy) + cz * cz;
  u64 key[32];
  {
    u64 initk = ((u64)(__float_as_uint(3e38f) ^ 0x80000000u) << 32) | 0xFFFFFFFFull;
    #pragma unroll
    for (int j = 0; j < 32; ++j) key[j] = initk;
  }
  float kthf = 3e38f;

  auto insert = [&](u64 cand) {   // ascending sorted insert, static indexing only
    bool cprev = false; u64 kprev = 0;
    #pragma unroll
    for (int j = 0; j < 32; ++j) {
      bool cj = cand < key[j];
      u64 cur = key[j];
      u64 nv = cj ? cand : cur;
      key[j] = cprev ? kprev : nv;
      cprev = cj; kprev = cur;
    }
    unsigned hb = (unsigned)(key[31] >> 32);
    unsigned ob = (hb & 0x80000000u) ? (hb ^ 0x80000000u) : ~hb;
    kthf = __uint_as_float(ob);
  };

  int cnt = 0;
  auto flush = [&]() {
    int mc = cnt;
    #pragma unroll
    for (int off = 1; off < 64; off <<= 1) { int o = __shfl_xor(mc, off); mc = o > mc ? o : mc; }
    for (int i = 0; i < mc; ++i) {
      u64 cand = ((u64)bhi[i * 512 + tid] << 32) | blo[i * 512 + tid];
      if (i < cnt && cand < key[31]) insert(cand);   // exact (d2,idx) lex decision
    }
    cnt = 0;
  };

  const int nbase = __builtin_amdgcn_readfirstlane(w * 1024);  // force SGPR -> s_load path
  const float4* pb = pts4 + (size_t)b * NN + nbase;
  for (int n0 = 0; n0 < 1024; n0 += 8) {
    #pragma unroll
    for (int j = 0; j < 8; ++j) {
      int n = n0 + j;
      float4 p = pb[n];
      float dot = fmaf(cz, p.z, fmaf(cy, p.y, cx * p.x));  // verified np-exact form
      float d2 = (cn2 + p.w) - 2.0f * dot;                  // separate ufunc ops
      if (d2 <= kthf) {                                     // exact re-check at insert
        unsigned db = __float_as_uint(d2);
        unsigned fk = db ^ (((int)db < 0) ? 0xFFFFFFFFu : 0x80000000u);
        blo[cnt * 512 + tid] = (unsigned)(nbase + n);
        bhi[cnt * 512 + tid] = fk;
        cnt++;
      }
    }
    if (__ballot(cnt >= 9)) flush();   // cap 16: <=8 carried + <=8 new
  }
  flush();
  __syncthreads();   // all waves done scanning; buffers dead -> marea aliasing safe

  auto publish = [&](int a) {
    u64* ap = marea + a * 2048;
    #pragma unroll
    for (int j = 0; j < 32; ++j) ap[j * 64 + lane] = key[j];   // [j][lane]: bank-free
  };
  auto merge_from = [&](int a) {
    u64* ap = marea + a * 2048;
    for (int j = 0; j < 32; ++j) {
      u64 cand = ap[j * 64 + lane];
      if (cand < key[31]) insert(cand);    // exact pairwise min-32 merge
    }
  };
  // tree merge 8->4->2->1 (all barriers at top level)
  if (w & 1) publish(w >> 1);
  __syncthreads();
  if (!(w & 1)) merge_from(w >> 1);
  __syncthreads();
  if (w == 2) publish(0);
  if (w == 6) publish(1);
  __syncthreads();
  if (w == 0) merge_from(0);
  if (w == 4) merge_from(1);
  __syncthreads();
  if (w == 4) publish(0);
  __syncthreads();
  if (w == 0) {
    merge_from(0);
    int* op = knnout + ((size_t)b * MM + m) * KNN;
    #pragma unroll
    for (int j = 0; j < 32; ++j) op[j] = (int)(key[j] & 0xFFFFFFFFull);
  }
}

// ---------------- K3: gather + conv1 -> y1 bf16 (B,M,k,64) --------------------
__global__ __launch_bounds__(256) void conv1_kernel(const float* __restrict__ xyz,
                                                    const float* __restrict__ feat,
                                                    const float* __restrict__ cent,
                                                    const int* __restrict__ knn,
                                                    const float* __restrict__ w1,
                                                    const float* __restrict__ b1,
                                                    unsigned short* __restrict__ y1) {
  int t = blockIdx.x * 256 + threadIdx.x;            // (b,m,kk) flattened
  int m = (t >> 5) & (MM - 1);
  int b = t >> 15;
  int idx = knn[t];
  const float* cp = cent + ((size_t)b * MM + m) * 3;
  const float* pp = xyz + ((size_t)b * NN + idx) * 3;
  float gf[3 + CIN];
  {
    #pragma clang fp contract(off)
    gf[0] = pp[0] - cp[0]; gf[1] = pp[1] - cp[1]; gf[2] = pp[2] - cp[2];
  }
  const float4* fp = (const float4*)(feat + ((size_t)b * NN + idx) * CIN);
  #pragma unroll
  for (int j = 0; j < 16; ++j) {
    float4 v = fp[j];
    gf[3 + 4 * j] = v.x; gf[4 + 4 * j] = v.y; gf[5 + 4 * j] = v.z; gf[6 + 4 * j] = v.w;
  }
  unsigned short* outp = y1 + (size_t)t * 64;
  for (int o4 = 0; o4 < 16; ++o4) {
    const float* w0 = w1 + (o4 * 4) * 67;
    float a0 = b1[o4 * 4 + 0], a1v = b1[o4 * 4 + 1], a2v = b1[o4 * 4 + 2], a3v = b1[o4 * 4 + 3];
    #pragma unroll
    for (int c = 0; c < 67; ++c) {
      float g = gf[c];
      a0  = fmaf(w0[c], g, a0);
      a1v = fmaf(w0[67 + c], g, a1v);
      a2v = fmaf(w0[134 + c], g, a2v);
      a3v = fmaf(w0[201 + c], g, a3v);
    }
    ushort4 sv;
    sv.x = f2bf(a0); sv.y = f2bf(a1v); sv.z = f2bf(a2v); sv.w = f2bf(a3v);
    *(ushort4*)(outp + o4 * 4) = sv;
  }
}

// ---------------- K3b: per-channel sum/sumsq of y1 (bf16) ---------------------
__global__ __launch_bounds__(256) void red1_kernel(const unsigned short* __restrict__ y1,
                                                   float* __restrict__ sums1) {
  __shared__ float acc[128];
  int tid = threadIdx.x;
  if (tid < 128) acc[tid] = 0.0f;
  __syncthreads();
  const ushort4* yp = (const ushort4*)(y1 + (size_t)blockIdx.x * 65536);
  int c0 = (4 * tid) & 63;
  float s0 = 0, s1 = 0, s2 = 0, s3 = 0, q0 = 0, q1 = 0, q2 = 0, q3 = 0;
  for (int it = 0; it < 64; ++it) {
    ushort4 v = yp[it * 256 + tid];
    float x = bf2f(v.x), y = bf2f(v.y), z = bf2f(v.z), w = bf2f(v.w);
    s0 += x; q0 = fmaf(x, x, q0);
    s1 += y; q1 = fmaf(y, y, q1);
    s2 += z; q2 = fmaf(z, z, q2);
    s3 += w; q3 = fmaf(w, w, q3);
  }
  atomicAdd(&acc[c0], s0); atomicAdd(&acc[c0 + 1], s1);
  atomicAdd(&acc[c0 + 2], s2); atomicAdd(&acc[c0 + 3], s3);
  atomicAdd(&acc[64 + c0], q0); atomicAdd(&acc[64 + c0 + 1], q1);
  atomicAdd(&acc[64 + c0 + 2], q2); atomicAdd(&acc[64 + c0 + 3], q3);
  __syncthreads();
  if (tid < 128) {
    int b = blockIdx.x >> 5;
    atomicAdd(&sums1[b * 128 + tid], acc[tid]);
  }
}

// ---------------- coeffs: GN (sums -> per-channel affine a,d) -----------------
__global__ void coeffs_kernel(const float* __restrict__ sums,
                              const float* __restrict__ gamma,
                              const float* __restrict__ beta,
                              float* __restrict__ a, float* __restrict__ d,
                              int nch, int cpg, float invn) {
  int t = blockIdx.x * blockDim.x + threadIdx.x;
  if (t >= BB * nch) return;
  int b = t / nch, c = t % nch, g = c / cpg;
  float S = 0, Q = 0;
  for (int j = 0; j < cpg; ++j) {
    S += sums[b * 2 * nch + g * cpg + j];
    Q += sums[b * 2 * nch + nch + g * cpg + j];
  }
  float mu = S * invn;
  float var = Q * invn - mu * mu;
  float rs = 1.0f / sqrtf(var + 1e-5f);
  float ga = gamma[c];
  a[t] = rs * ga;
  d[t] = beta[c] - mu * rs * ga;
}

// ============ MFMA conv2 common: per-wave z = h(32x64) . W2^T(64x128) =========
struct Conv2Frag {
  bf16x8 bfr[8][2];   // [ntile][kstep]
  float  b2v[8];
};

__device__ __forceinline__ void load_w2_frags(const unsigned short* __restrict__ w2b,
                                              const float* __restrict__ b2,
                                              int lane, Conv2Frag& F) {
  const int quad = lane >> 4, lr = lane & 15;
  #pragma unroll
  for (int nt = 0; nt < 8; ++nt) {
    #pragma unroll
    for (int t = 0; t < 2; ++t)
      F.bfr[nt][t] = *(const bf16x8*)(w2b + (size_t)(nt * 16 + lr) * 64 + t * 32 + quad * 8);
    F.b2v[nt] = b2[nt * 16 + lr];
  }
}

__device__ __forceinline__ void conv2_wave_mfma(const unsigned short* __restrict__ y1,
                                                const float* __restrict__ a1,
                                                const float* __restrict__ d1,
                                                unsigned short* __restrict__ hrow, // [32][72]
                                                int wid, int b, int lane,
                                                const Conv2Frag& F,
                                                f32x4 acc[2][8]) {
  const int quad = lane >> 4, lr = lane & 15;
  const int r = lane >> 1, c0 = (lane & 1) * 32;
  const unsigned short* yrow = y1 + (size_t)wid * 2048 + r * 64 + c0;
  const float* ap = a1 + b * 64 + c0;
  const float* dp = d1 + b * 64 + c0;
  #pragma unroll
  for (int g = 0; g < 4; ++g) {
    bf16x8 v = *(const bf16x8*)(yrow + 8 * g);
    float4 av0 = *(const float4*)(ap + 8 * g),     dv0 = *(const float4*)(dp + 8 * g);
    float4 av1 = *(const float4*)(ap + 8 * g + 4), dv1 = *(const float4*)(dp + 8 * g + 4);
    bf16x8 h;
    h[0] = (short)f2bf(fmaxf(0.0f, fmaf(bf2f((unsigned short)v[0]), av0.x, dv0.x)));
    h[1] = (short)f2bf(fmaxf(0.0f, fmaf(bf2f((unsigned short)v[1]), av0.y, dv0.y)));
    h[2] = (short)f2bf(fmaxf(0.0f, fmaf(bf2f((unsigned short)v[2]), av0.z, dv0.z)));
    h[3] = (short)f2bf(fmaxf(0.0f, fmaf(bf2f((unsigned short)v[3]), av0.w, dv0.w)));
    h[4] = (short)f2bf(fmaxf(0.0f, fmaf(bf2f((unsigned short)v[4]), av1.x, dv1.x)));
    h[5] = (short)f2bf(fmaxf(0.0f, fmaf(bf2f((unsigned short)v[5]), av1.y, dv1.y)));
    h[6] = (short)f2bf(fmaxf(0.0f, fmaf(bf2f((unsigned short)v[6]), av1.z, dv1.z)));
    h[7] = (short)f2bf(fmaxf(0.0f, fmaf(bf2f((unsigned short)v[7]), av1.w, dv1.w)));
    *(bf16x8*)(hrow + r * 72 + c0 + 8 * g) = h;
  }
  __builtin_amdgcn_s_waitcnt(0);            // drain lds writes (same wave consumes)
  __builtin_amdgcn_wave_barrier();
  #pragma unroll
  for (int mt = 0; mt < 2; ++mt)
    #pragma unroll
    for (int nt = 0; nt < 8; ++nt)
      acc[mt][nt] = (f32x4){0.f, 0.f, 0.f, 0.f};
  #pragma unroll
  for (int t = 0; t < 2; ++t) {
    bf16x8 a0 = *(const bf16x8*)(hrow + (0 + lr) * 72 + t * 32 + quad * 8);
    bf16x8 a1f = *(const bf16x8*)(hrow + (16 + lr) * 72 + t * 32 + quad * 8);
    #pragma unroll
    for (int nt = 0; nt < 8; ++nt) {
      acc[0][nt] = __builtin_amdgcn_mfma_f32_16x16x32_bf16(a0,  F.bfr[nt][t], acc[0][nt], 0, 0, 0);
      acc[1][nt] = __builtin_amdgcn_mfma_f32_16x16x32_bf16(a1f, F.bfr[nt][t], acc[1][nt], 0, 0, 0);
    }
  }
}

// ---------------- K5: conv2 (MFMA) -> GN2 stats -------------------------------
__global__ __launch_bounds__(256) void conv2_stats_kernel(const unsigned short* __restrict__ y1,
                                                          const float* __restrict__ a1,
                                                          const float* __restrict__ d1,
                                                          const unsigned short* __restrict__ w2b,
                                                          const float* __restrict__ b2,
                                                          float* __restrict__ sums2) {
  __shared__ __align__(16) unsigned short hsm[4][32 * 72];
  __shared__ float sacc[128], qacc[128];
  const int tid = threadIdx.x, lane = tid & 63, w = tid >> 6;
  const int wid = blockIdx.x * 4 + w;
  const int b = blockIdx.x >> 8;
  if (tid < 128) { sacc[tid] = 0.0f; qacc[tid] = 0.0f; }
  __syncthreads();
  Conv2Frag F;
  load_w2_frags(w2b, b2, lane, F);
  f32x4 acc[2][8];
  conv2_wave_mfma(y1, a1, d1, hsm[w], wid, b, lane, F, acc);
  const int lr = lane & 15;
  #pragma unroll
  for (int nt = 0; nt < 8; ++nt) {
    float s = 0, q = 0;
    #pragma unroll
    for (int mt = 0; mt < 2; ++mt)
      #pragma unroll
      for (int rg = 0; rg < 4; ++rg) {
        float z = acc[mt][nt][rg] + F.b2v[nt];
        s += z; q = fmaf(z, z, q);
      }
    atomicAdd(&sacc[nt * 16 + lr], s);
    atomicAdd(&qacc[nt * 16 + lr], q);
  }
  __syncthreads();
  if (tid < 128) {
    atomicAdd(&sums2[b * 256 + tid], sacc[tid]);
    atomicAdd(&sums2[b * 256 + 128 + tid], qacc[tid]);
  }
}

// ---------------- K7: conv2 (MFMA) + GN2 + relu + max over k -> new_feat ------
__global__ __launch_bounds__(256) void final_kernel(const unsigned short* __restrict__ y1,
                                                    const float* __restrict__ a1,
                                                    const float* __restrict__ d1,
                                                    const unsigned short* __restrict__ w2b,
                                                    const float* __restrict__ b2,
                                                    const float* __restrict__ a2,
                                                    const float* __restrict__ d2,
                                                    float* __restrict__ nf) {
  __shared__ __align__(16) unsigned short hsm[4][32 * 72];
  const int tid = threadIdx.x, lane = tid & 63, w = tid >> 6;
  const int wid = blockIdx.x * 4 + w;
  const int b = blockIdx.x >> 8;
  Conv2Frag F;
  load_w2_frags(w2b, b2, lane, F);
  f32x4 acc[2][8];
  conv2_wave_mfma(y1, a1, d1, hsm[w], wid, b, lane, F, acc);
  const int lr = lane & 15;
  float az[8], dz[8];
  #pragma unroll
  for (int nt = 0; nt < 8; ++nt) {
    az[nt] = a2[b * 128 + nt * 16 + lr];
    dz[nt] = d2[b * 128 + nt * 16 + lr];
  }
  float pmax[8];
  #pragma unroll
  for (int nt = 0; nt < 8; ++nt) {
    float mx = -3e38f;
    #pragma unroll
    for (int mt = 0; mt < 2; ++mt)
      #pragma unroll
      for (int rg = 0; rg < 4; ++rg) {
        float z = acc[mt][nt][rg] + F.b2v[nt];
        float v = fmaxf(0.0f, fmaf(z, az[nt], dz[nt]));
        mx = fmaxf(mx, v);
      }
    mx = fmaxf(mx, __shfl_xor(mx, 16));
    mx = fmaxf(mx, __shfl_xor(mx, 32));
    pmax[nt] = mx;
  }
  if (lane < 16) {
    float* op = nf + (size_t)wid * 128;
    #pragma unroll
    for (int nt = 0; nt < 8; ++nt) op[nt * 16 + lr] = pmax[nt];
  }
}

extern "C" void kernel_launch(void* const* d_in, const int* in_sizes, int n_in,
                              void* d_out, int out_size, void* d_ws, size_t ws_size,
                              hipStream_t stream) {
  const float* xyz  = (const float*)d_in[0];
  const float* feat = (const float*)d_in[1];
  const float* w1   = (const float*)d_in[2];
  const float* b1   = (const float*)d_in[3];
  const float* g1w  = (const float*)d_in[4];
  const float* g1b  = (const float*)d_in[5];
  const float* w2   = (const float*)d_in[6];
  const float* b2   = (const float*)d_in[7];
  const float* g2w  = (const float*)d_in[8];
  const float* g2b  = (const float*)d_in[9];
  float* ws = (float*)d_ws;
  float* cent = (float*)d_out;                    // (B,M,3)
  float* nf   = (float*)d_out + BB * MM * 3;      // (B,M,128)
  const float4* pts4 = (const float4*)(ws + PTS4_OFF);
  int*   knn   = (int*)(ws + KNN_OFF);
  float* sums1 = ws + SUM1_OFF;
  float* sums2 = ws + SUM2_OFF;
  float* a1 = ws + A1_OFF; float* d1 = ws + D1_OFF;
  float* a2 = ws + A2_OFF; float* d2 = ws + D2_OFF;
  const unsigned short* w2b = (const unsigned short*)(ws + W2B_OFF);
  unsigned short* y1 = (unsigned short*)(ws + Y1_OFF);

  hipLaunchKernelGGL(k0_init, dim3(512), dim3(256), 0, stream, xyz, w2, ws);
  hipLaunchKernelGGL(fps_kernel, dim3(16), dim3(256), 0, stream, xyz, cent);
  hipLaunchKernelGGL(knn_kernel, dim3(256), dim3(512), 0, stream, pts4, cent, knn);
  hipLaunchKernelGGL(conv1_kernel, dim3(2048), dim3(256), 0, stream,
                     xyz, feat, cent, knn, w1, b1, y1);
  hipLaunchKernelGGL(red1_kernel, dim3(512), dim3(256), 0, stream, y1, sums1);
  hipLaunchKernelGGL(coeffs_kernel, dim3(4), dim3(256), 0, stream,
                     sums1, g1w, g1b, a1, d1, 64, 2, 1.0f / 65536.0f);
  hipLaunchKernelGGL(conv2_stats_kernel, dim3(4096), dim3(256), 0, stream,
                     y1, a1, d1, w2b, b2, sums2);
  hipLaunchKernelGGL(coeffs_kernel, dim3(8), dim3(256), 0, stream,
                     sums2, g2w, g2b, a2, d2, 128, 4, 1.0f / 131072.0f);
  hipLaunchKernelGGL(final_kernel, dim3(4096), dim3(256), 0, stream,
                     y1, a1, d1, w2b, b2, a2, d2, nf);
}

// Round 15
// 1567.289 us; speedup vs baseline: 1.1329x; 1.1329x over previous
//
#include <hip/hip_runtime.h>
#include <cstdint>

#define BB 16
#define NN 8192
#define MM 1024
#define KNN 32
#define CIN 64
#define HID 64
#define OCH 128

// workspace float offsets
#define KNN_OFF   0u          // 524288 ints
#define SUM1_OFF  524288u     // 2048
#define SUM2_OFF  526336u     // 4096
#define A1_OFF    530432u     // 1024
#define D1_OFF    531456u     // 1024
#define A2_OFF    532480u     // 2048
#define D2_OFF    534528u     // 2048
#define W2B_OFF   536576u     // 4096 floats = 8192 bf16 (w2 pre-converted)
#define W1B_OFF   540672u     // 3072 floats = 6144 bf16 (w1 padded 67->96, bf16)
#define Y1_OFF    543744u     // y1 f32: 33554432 floats; pts4 aliases head
#define PTS4_OFF  Y1_OFF      // 131072 float4 (dead once conv1 runs)

typedef unsigned long long u64;
typedef float f32x4 __attribute__((ext_vector_type(4)));
typedef float f32x2 __attribute__((ext_vector_type(2)));
typedef short bf16x8 __attribute__((ext_vector_type(8)));

__device__ __forceinline__ unsigned short f2bf(float f) {
  union { float f; unsigned u; } v; v.f = f;
  unsigned r = v.u + 0x7FFFu + ((v.u >> 16) & 1u);   // RNE
  return (unsigned short)(r >> 16);
}

// ---------------- K0: zero stats + pts4 + w2->bf16 + w1->padded bf16 ----------
__global__ __launch_bounds__(256) void k0_init(const float* __restrict__ xyz,
                                               const float* __restrict__ w1,
                                               const float* __restrict__ w2,
                                               float* __restrict__ ws) {
  int t = blockIdx.x * 256 + threadIdx.x;
  if (t < 12288) ws[SUM1_OFF + t] = 0.0f;
  if (t < 4096) {   // w2: 128x64 f32 -> bf16 pairs (RNE)
    unsigned lo = f2bf(w2[2 * t]);
    unsigned hi = f2bf(w2[2 * t + 1]);
    ((unsigned*)(ws + W2B_OFF))[t] = lo | (hi << 16);
  }
  if (t < 6144) {   // w1b[n][kk]: kk 0..2 = w1[n][0..2]; kk==3 dummy 0;
                    // kk 4..67 = w1[n][kk-1]; kk 68..95 = 0 (K pad for MFMA)
    int n = t / 96, kk = t % 96;
    float val = 0.0f;
    if (kk < 3) val = w1[n * 67 + kk];
    else if (kk >= 4 && kk < 68) val = w1[n * 67 + kk - 1];
    ((unsigned short*)(ws + W1B_OFF))[t] = f2bf(val);
  }
  if (t < BB * NN) {
    #pragma clang fp contract(off)
    float x = xyz[(size_t)t * 3], y = xyz[(size_t)t * 3 + 1], z = xyz[(size_t)t * 3 + 2];
    ((float4*)(ws + PTS4_OFF))[t] = make_float4(x, y, z, (x * x + y * y) + z * z);
  }
}

// DPP u64 max-reduction across a wave; full max lands in lane 63.
__device__ __forceinline__ u64 wave_max_u64(u64 v) {
  #define DPP_RND(ctrl, rm)                                                     \
  {                                                                             \
    int lo_ = __builtin_amdgcn_update_dpp(0, (int)(unsigned)(v & 0xFFFFFFFFull),\
                                          ctrl, rm, 0xf, true);                 \
    int hi_ = __builtin_amdgcn_update_dpp(0, (int)(unsigned)(v >> 32),          \
                                          ctrl, rm, 0xf, true);                 \
    u64 o_ = ((u64)(unsigned)hi_ << 32) | (unsigned)lo_;                        \
    v = o_ > v ? o_ : v;                                                        \
  }
  DPP_RND(0x111, 0xf)  // row_shr:1
  DPP_RND(0x112, 0xf)  // row_shr:2
  DPP_RND(0x114, 0xf)  // row_shr:4
  DPP_RND(0x118, 0xf)  // row_shr:8
  DPP_RND(0x142, 0xa)  // row_bcast:15 -> rows 1,3
  DPP_RND(0x143, 0xc)  // row_bcast:31 -> rows 2,3
  #undef DPP_RND
  return v;
}

// ---------------- K1: FPS — 256 thr (4 waves, 1/SIMD), packed distance --------
// Verified R14 form (840 us). SCALAR tie semantics preserved; packed IEEE slots.
__global__ __launch_bounds__(256) void fps_kernel(const float* __restrict__ xyz,
                                                  float* __restrict__ cent) {
  #pragma clang fp contract(off)
  __shared__ float4 sp4[NN];     // 128 KB
  __shared__ u64 slots[MM];      // 8 KB
  const int b = blockIdx.x, tid = threadIdx.x;
  const float* xp = xyz + (size_t)b * NN * 3;
  f32x2 px[16], py[16], pz[16];
  float dist0[16], dist1[16];
  #pragma unroll
  for (int i = 0; i < 16; ++i) {
    int n0 = tid + (2 * i) * 256, n1 = tid + (2 * i + 1) * 256;
    float x0 = xp[n0 * 3], y0 = xp[n0 * 3 + 1], z0 = xp[n0 * 3 + 2];
    float x1 = xp[n1 * 3], y1 = xp[n1 * 3 + 1], z1 = xp[n1 * 3 + 2];
    px[i] = (f32x2){x0, x1}; py[i] = (f32x2){y0, y1}; pz[i] = (f32x2){z0, z1};
    sp4[n0] = make_float4(x0, y0, z0, 0.0f);
    sp4[n1] = make_float4(x1, y1, z1, 0.0f);
    dist0[i] = 1e10f; dist1[i] = 1e10f;
  }
  for (int s = tid; s < MM; s += 256) slots[s] = 0ull;
  __syncthreads();
  int far = 0;
  float* co = cent + (size_t)b * MM * 3;
  for (int step = 0; step < MM; ++step) {
    float4 c4 = sp4[far];
    if (tid == 0) { co[step * 3] = c4.x; co[step * 3 + 1] = c4.y; co[step * 3 + 2] = c4.z; }
    f32x2 cx = (f32x2){c4.x, c4.x}, cy = (f32x2){c4.y, c4.y}, cz = (f32x2){c4.z, c4.z};
    float best = -1.0f; int bi = 0;
    #pragma unroll
    for (int i = 0; i < 16; ++i) {
      f32x2 dx = px[i] - cx, dy = py[i] - cy, dz = pz[i] - cz;
      f32x2 d = (dx * dx + dy * dy) + dz * dz;   // np: left-assoc, no fma (per slot)
      float dm0 = fminf(dist0[i], d.x);
      float dm1 = fminf(dist1[i], d.y);
      dist0[i] = dm0; dist1[i] = dm1;
      if (dm0 > best) { best = dm0; bi = tid + (2 * i) * 256; }      // strict >: lowest n
      if (dm1 > best) { best = dm1; bi = tid + (2 * i + 1) * 256; }
    }
    u64 key = ((u64)__float_as_uint(best) << 32) | (unsigned)(8191 - bi);
    key = wave_max_u64(key);
    if ((tid & 63) == 63) atomicMax(&slots[step], key);   // max dist, tie -> lowest idx
    __syncthreads();
    far = 8191 - (int)(unsigned)(slots[step] & 0xFFFFFFFFull);
  }
}

// ---------------- K2: kNN — 8-way N-split, bank-free buffers, tree merge ------
__global__ __launch_bounds__(512) void knn_kernel(const float4* __restrict__ pts4,
                                                  const float* __restrict__ cent,
                                                  int* __restrict__ knnout) {
  #pragma clang fp contract(off)
  __shared__ __align__(16) char smem[65536];
  unsigned* blo = (unsigned*)smem;              // [16][512] cand idx (bank-free)
  unsigned* bhi = (unsigned*)(smem + 32768);    // [16][512] cand key-hi
  u64* marea = (u64*)smem;                      // 4 areas x [32][64]; aliases buffers
                                                // AFTER the post-scan barrier (R5 lesson)
  const int tid = threadIdx.x;
  const int lane = tid & 63;
  const int w = tid >> 6;          // wave id = N-octant
  const int b = blockIdx.x >> 4;
  const int m = ((blockIdx.x & 15) << 6) + lane;
  const float* cp = cent + ((size_t)b * MM + m) * 3;
  float cx = cp[0], cy = cp[1], cz = cp[2];
  float cn2 = (cx * cx + cy * cy) + cz * cz;
  u64 key[32];
  {
    u64 initk = ((u64)(__float_as_uint(3e38f) ^ 0x80000000u) << 32) | 0xFFFFFFFFull;
    #pragma unroll
    for (int j = 0; j < 32; ++j) key[j] = initk;
  }
  float kthf = 3e38f;

  auto insert = [&](u64 cand) {   // ascending sorted insert, static indexing only
    bool cprev = false; u64 kprev = 0;
    #pragma unroll
    for (int j = 0; j < 32; ++j) {
      bool cj = cand < key[j];
      u64 cur = key[j];
      u64 nv = cj ? cand : cur;
      key[j] = cprev ? kprev : nv;
      cprev = cj; kprev = cur;
    }
    unsigned hb = (unsigned)(key[31] >> 32);
    unsigned ob = (hb & 0x80000000u) ? (hb ^ 0x80000000u) : ~hb;
    kthf = __uint_as_float(ob);
  };

  int cnt = 0;
  auto flush = [&]() {
    int mc = cnt;
    #pragma unroll
    for (int off = 1; off < 64; off <<= 1) { int o = __shfl_xor(mc, off); mc = o > mc ? o : mc; }
    for (int i = 0; i < mc; ++i) {
      u64 cand = ((u64)bhi[i * 512 + tid] << 32) | blo[i * 512 + tid];
      if (i < cnt && cand < key[31]) insert(cand);   // exact (d2,idx) lex decision
    }
    cnt = 0;
  };

  const int nbase = __builtin_amdgcn_readfirstlane(w * 1024);  // force SGPR -> s_load path
  const float4* pb = pts4 + (size_t)b * NN + nbase;
  for (int n0 = 0; n0 < 1024; n0 += 8) {
    #pragma unroll
    for (int j = 0; j < 8; ++j) {
      int n = n0 + j;
      float4 p = pb[n];
      float dot = fmaf(cz, p.z, fmaf(cy, p.y, cx * p.x));  // verified np-exact form
      float d2 = (cn2 + p.w) - 2.0f * dot;                  // separate ufunc ops
      if (d2 <= kthf) {                                     // exact re-check at insert
        unsigned db = __float_as_uint(d2);
        unsigned fk = db ^ (((int)db < 0) ? 0xFFFFFFFFu : 0x80000000u);
        blo[cnt * 512 + tid] = (unsigned)(nbase + n);
        bhi[cnt * 512 + tid] = fk;
        cnt++;
      }
    }
    if (__ballot(cnt >= 9)) flush();   // cap 16: <=8 carried + <=8 new
  }
  flush();
  __syncthreads();   // all waves done scanning; buffers dead -> marea aliasing safe

  auto publish = [&](int a) {
    u64* ap = marea + a * 2048;
    #pragma unroll
    for (int j = 0; j < 32; ++j) ap[j * 64 + lane] = key[j];   // [j][lane]: bank-free
  };
  auto merge_from = [&](int a) {
    u64* ap = marea + a * 2048;
    for (int j = 0; j < 32; ++j) {
      u64 cand = ap[j * 64 + lane];
      if (cand < key[31]) insert(cand);    // exact pairwise min-32 merge
    }
  };
  // tree merge 8->4->2->1 (all barriers at top level)
  if (w & 1) publish(w >> 1);
  __syncthreads();
  if (!(w & 1)) merge_from(w >> 1);
  __syncthreads();
  if (w == 2) publish(0);
  if (w == 6) publish(1);
  __syncthreads();
  if (w == 0) merge_from(0);
  if (w == 4) merge_from(1);
  __syncthreads();
  if (w == 4) publish(0);
  __syncthreads();
  if (w == 0) {
    merge_from(0);
    int* op = knnout + ((size_t)b * MM + m) * KNN;
    #pragma unroll
    for (int j = 0; j < 32; ++j) op[j] = (int)(key[j] & 0xFFFFFFFFull);
  }
}

// ---------------- K3: conv1 via MFMA — per-wave (b,m): [32x96]x[96x64] --------
// A-frag: A[m=lane&15][k=quad*8+j] from LDS gf[32][104] bf16
// B-frag: B[k][n=lane&15] = w1b[n][k] (padded K layout; zeros kill pad lanes)
// D:      D[m=quad*4+reg][n=lane&15]  (verified m89/m91 mapping, same as conv2)
__global__ __launch_bounds__(256) void conv1_kernel(const float* __restrict__ xyz,
                                                    const float* __restrict__ feat,
                                                    const float* __restrict__ cent,
                                                    const int* __restrict__ knn,
                                                    const unsigned short* __restrict__ w1b,
                                                    const float* __restrict__ b1,
                                                    float* __restrict__ y1) {
  __shared__ __align__(16) unsigned short gsm[4][32 * 104];
  const int tid = threadIdx.x, lane = tid & 63, w = tid >> 6;
  const int wid = blockIdx.x * 4 + w;           // (b,m) pair 0..16383
  const int b = wid >> 10;
  unsigned short* gf = gsm[w];

  int idxv = 0;
  if (lane < 32) idxv = knn[(size_t)wid * 32 + lane];

  // zero K-pad [64..96) per row (feat phase below overwrites [64..67])
  {
    int row = lane >> 1, h = (lane & 1) * 16;
    ushort4 z4 = {0, 0, 0, 0};
    *(ushort4*)(gf + row * 104 + 64 + h + 0)  = z4;
    *(ushort4*)(gf + row * 104 + 64 + h + 4)  = z4;
    *(ushort4*)(gf + row * 104 + 64 + h + 8)  = z4;
    *(ushort4*)(gf + row * 104 + 64 + h + 12) = z4;
  }
  // delta rows (lanes 0..31): gf[r][0..2] = xyz[idx]-cent, gf[r][3] = dummy 0
  const float* cp = cent + (size_t)wid * 3;
  float ccx = cp[0], ccy = cp[1], ccz = cp[2];
  if (lane < 32) {
    const float* pp = xyz + ((size_t)b * NN + idxv) * 3;
    ushort4 dv;
    dv.x = f2bf(pp[0] - ccx); dv.y = f2bf(pp[1] - ccy); dv.z = f2bf(pp[2] - ccz);
    dv.w = 0;
    *(ushort4*)(gf + lane * 104) = dv;
  }
  // feat: 512 float4s staged cooperatively, gf[row][4 + part*4 ..] bf16
  const float4* fb = (const float4*)feat;
  #pragma unroll
  for (int i = 0; i < 8; ++i) {
    int v = i * 64 + lane;
    int row = v >> 4, part = v & 15;
    int ridx = __shfl(idxv, row);
    float4 f4 = fb[(size_t)(b * NN + ridx) * 16 + part];
    ushort4 s;
    s.x = f2bf(f4.x); s.y = f2bf(f4.y); s.z = f2bf(f4.z); s.w = f2bf(f4.w);
    *(ushort4*)(gf + row * 104 + 4 + part * 4) = s;
  }
  __builtin_amdgcn_s_waitcnt(0);
  __builtin_amdgcn_wave_barrier();

  const int quad = lane >> 4, lr = lane & 15;
  bf16x8 bw[4][3];
  float b1v[4];
  #pragma unroll
  for (int nt = 0; nt < 4; ++nt) {
    #pragma unroll
    for (int ks = 0; ks < 3; ++ks)
      bw[nt][ks] = *(const bf16x8*)(w1b + (size_t)(nt * 16 + lr) * 96 + ks * 32 + quad * 8);
    b1v[nt] = b1[nt * 16 + lr];
  }
  f32x4 acc[2][4];
  #pragma unroll
  for (int mt = 0; mt < 2; ++mt)
    #pragma unroll
    for (int nt = 0; nt < 4; ++nt)
      acc[mt][nt] = (f32x4){0.f, 0.f, 0.f, 0.f};
  #pragma unroll
  for (int ks = 0; ks < 3; ++ks) {
    bf16x8 a0 = *(const bf16x8*)(gf + (0 + lr) * 104 + ks * 32 + quad * 8);
    bf16x8 a1 = *(const bf16x8*)(gf + (16 + lr) * 104 + ks * 32 + quad * 8);
    #pragma unroll
    for (int nt = 0; nt < 4; ++nt) {
      acc[0][nt] = __builtin_amdgcn_mfma_f32_16x16x32_bf16(a0, bw[nt][ks], acc[0][nt], 0, 0, 0);
      acc[1][nt] = __builtin_amdgcn_mfma_f32_16x16x32_bf16(a1, bw[nt][ks], acc[1][nt], 0, 0, 0);
    }
  }
  float* yo = y1 + (size_t)wid * 2048;
  #pragma unroll
  for (int mt = 0; mt < 2; ++mt)
    #pragma unroll
    for (int rg = 0; rg < 4; ++rg) {
      int row = mt * 16 + quad * 4 + rg;
      #pragma unroll
      for (int nt = 0; nt < 4; ++nt)
        yo[row * 64 + nt * 16 + lr] = acc[mt][nt][rg] + b1v[nt];
    }
}

// ---------------- K3b: per-channel sum/sumsq of y1 (f32, R13 verified) --------
__global__ __launch_bounds__(256) void red1_kernel(const float* __restrict__ y1,
                                                   float* __restrict__ sums1) {
  __shared__ float acc[128];
  int tid = threadIdx.x;
  if (tid < 128) acc[tid] = 0.0f;
  __syncthreads();
  const float4* yp = (const float4*)(y1 + (size_t)blockIdx.x * 65536);
  int c0 = (4 * tid) & 63;
  float s0 = 0, s1 = 0, s2 = 0, s3 = 0, q0 = 0, q1 = 0, q2 = 0, q3 = 0;
  for (int it = 0; it < 64; ++it) {
    float4 v = yp[it * 256 + tid];
    s0 += v.x; q0 = fmaf(v.x, v.x, q0);
    s1 += v.y; q1 = fmaf(v.y, v.y, q1);
    s2 += v.z; q2 = fmaf(v.z, v.z, q2);
    s3 += v.w; q3 = fmaf(v.w, v.w, q3);
  }
  atomicAdd(&acc[c0], s0); atomicAdd(&acc[c0 + 1], s1);
  atomicAdd(&acc[c0 + 2], s2); atomicAdd(&acc[c0 + 3], s3);
  atomicAdd(&acc[64 + c0], q0); atomicAdd(&acc[64 + c0 + 1], q1);
  atomicAdd(&acc[64 + c0 + 2], q2); atomicAdd(&acc[64 + c0 + 3], q3);
  __syncthreads();
  if (tid < 128) {
    int b = blockIdx.x >> 5;
    atomicAdd(&sums1[b * 128 + tid], acc[tid]);
  }
}

// ---------------- coeffs: GN (sums -> per-channel affine a,d) -----------------
__global__ void coeffs_kernel(const float* __restrict__ sums,
                              const float* __restrict__ gamma,
                              const float* __restrict__ beta,
                              float* __restrict__ a, float* __restrict__ d,
                              int nch, int cpg, float invn) {
  int t = blockIdx.x * blockDim.x + threadIdx.x;
  if (t >= BB * nch) return;
  int b = t / nch, c = t % nch, g = c / cpg;
  float S = 0, Q = 0;
  for (int j = 0; j < cpg; ++j) {
    S += sums[b * 2 * nch + g * cpg + j];
    Q += sums[b * 2 * nch + nch + g * cpg + j];
  }
  float mu = S * invn;
  float var = Q * invn - mu * mu;
  float rs = 1.0f / sqrtf(var + 1e-5f);
  float ga = gamma[c];
  a[t] = rs * ga;
  d[t] = beta[c] - mu * rs * ga;
}

// ============ MFMA conv2 common (R13 verified, f32 y1) ========================
struct Conv2Frag {
  bf16x8 bfr[8][2];   // [ntile][kstep]
  float  b2v[8];
};

__device__ __forceinline__ void load_w2_frags(const unsigned short* __restrict__ w2b,
                                              const float* __restrict__ b2,
                                              int lane, Conv2Frag& F) {
  const int quad = lane >> 4, lr = lane & 15;
  #pragma unroll
  for (int nt = 0; nt < 8; ++nt) {
    #pragma unroll
    for (int t = 0; t < 2; ++t)
      F.bfr[nt][t] = *(const bf16x8*)(w2b + (size_t)(nt * 16 + lr) * 64 + t * 32 + quad * 8);
    F.b2v[nt] = b2[nt * 16 + lr];
  }
}

__device__ __forceinline__ void conv2_wave_mfma(const float* __restrict__ y1,
                                                const float* __restrict__ a1,
                                                const float* __restrict__ d1,
                                                unsigned short* __restrict__ hrow, // [32][72]
                                                int wid, int b, int lane,
                                                const Conv2Frag& F,
                                                f32x4 acc[2][8]) {
  const int quad = lane >> 4, lr = lane & 15;
  const int r = lane >> 1, c0 = (lane & 1) * 32;
  const float4* yrow = (const float4*)(y1 + (size_t)wid * 2048 + r * 64 + c0);
  const float4* ap = (const float4*)(a1 + b * 64 + c0);
  const float4* dp = (const float4*)(d1 + b * 64 + c0);
  #pragma unroll
  for (int g = 0; g < 8; ++g) {
    float4 v = yrow[g];
    float4 av = ap[g & 7], dv = dp[g & 7];
    ushort4 sv;
    sv.x = f2bf(fmaxf(0.0f, fmaf(v.x, av.x, dv.x)));
    sv.y = f2bf(fmaxf(0.0f, fmaf(v.y, av.y, dv.y)));
    sv.z = f2bf(fmaxf(0.0f, fmaf(v.z, av.z, dv.z)));
    sv.w = f2bf(fmaxf(0.0f, fmaf(v.w, av.w, dv.w)));
    *(ushort4*)(hrow + r * 72 + c0 + 4 * g) = sv;
  }
  __builtin_amdgcn_s_waitcnt(0);            // drain lds writes (same wave consumes)
  __builtin_amdgcn_wave_barrier();
  #pragma unroll
  for (int mt = 0; mt < 2; ++mt)
    #pragma unroll
    for (int nt = 0; nt < 8; ++nt)
      acc[mt][nt] = (f32x4){0.f, 0.f, 0.f, 0.f};
  #pragma unroll
  for (int t = 0; t < 2; ++t) {
    bf16x8 a0 = *(const bf16x8*)(hrow + (0 + lr) * 72 + t * 32 + quad * 8);
    bf16x8 a1f = *(const bf16x8*)(hrow + (16 + lr) * 72 + t * 32 + quad * 8);
    #pragma unroll
    for (int nt = 0; nt < 8; ++nt) {
      acc[0][nt] = __builtin_amdgcn_mfma_f32_16x16x32_bf16(a0,  F.bfr[nt][t], acc[0][nt], 0, 0, 0);
      acc[1][nt] = __builtin_amdgcn_mfma_f32_16x16x32_bf16(a1f, F.bfr[nt][t], acc[1][nt], 0, 0, 0);
    }
  }
}

// ---------------- K5: conv2 (MFMA) -> GN2 stats -------------------------------
__global__ __launch_bounds__(256) void conv2_stats_kernel(const float* __restrict__ y1,
                                                          const float* __restrict__ a1,
                                                          const float* __restrict__ d1,
                                                          const unsigned short* __restrict__ w2b,
                                                          const float* __restrict__ b2,
                                                          float* __restrict__ sums2) {
  __shared__ __align__(16) unsigned short hsm[4][32 * 72];
  __shared__ float sacc[128], qacc[128];
  const int tid = threadIdx.x, lane = tid & 63, w = tid >> 6;
  const int wid = blockIdx.x * 4 + w;
  const int b = blockIdx.x >> 8;
  if (tid < 128) { sacc[tid] = 0.0f; qacc[tid] = 0.0f; }
  __syncthreads();
  Conv2Frag F;
  load_w2_frags(w2b, b2, lane, F);
  f32x4 acc[2][8];
  conv2_wave_mfma(y1, a1, d1, hsm[w], wid, b, lane, F, acc);
  const int lr = lane & 15;
  #pragma unroll
  for (int nt = 0; nt < 8; ++nt) {
    float s = 0, q = 0;
    #pragma unroll
    for (int mt = 0; mt < 2; ++mt)
      #pragma unroll
      for (int rg = 0; rg < 4; ++rg) {
        float z = acc[mt][nt][rg] + F.b2v[nt];
        s += z; q = fmaf(z, z, q);
      }
    atomicAdd(&sacc[nt * 16 + lr], s);
    atomicAdd(&qacc[nt * 16 + lr], q);
  }
  __syncthreads();
  if (tid < 128) {
    atomicAdd(&sums2[b * 256 + tid], sacc[tid]);
    atomicAdd(&sums2[b * 256 + 128 + tid], qacc[tid]);
  }
}

// ---------------- K7: conv2 (MFMA) + GN2 + relu + max over k -> new_feat ------
__global__ __launch_bounds__(256) void final_kernel(const float* __restrict__ y1,
                                                    const float* __restrict__ a1,
                                                    const float* __restrict__ d1,
                                                    const unsigned short* __restrict__ w2b,
                                                    const float* __restrict__ b2,
                                                    const float* __restrict__ a2,
                                                    const float* __restrict__ d2,
                                                    float* __restrict__ nf) {
  __shared__ __align__(16) unsigned short hsm[4][32 * 72];
  const int tid = threadIdx.x, lane = tid & 63, w = tid >> 6;
  const int wid = blockIdx.x * 4 + w;
  const int b = blockIdx.x >> 8;
  Conv2Frag F;
  load_w2_frags(w2b, b2, lane, F);
  f32x4 acc[2][8];
  conv2_wave_mfma(y1, a1, d1, hsm[w], wid, b, lane, F, acc);
  const int lr = lane & 15;
  float az[8], dz[8];
  #pragma unroll
  for (int nt = 0; nt < 8; ++nt) {
    az[nt] = a2[b * 128 + nt * 16 + lr];
    dz[nt] = d2[b * 128 + nt * 16 + lr];
  }
  float pmax[8];
  #pragma unroll
  for (int nt = 0; nt < 8; ++nt) {
    float mx = -3e38f;
    #pragma unroll
    for (int mt = 0; mt < 2; ++mt)
      #pragma unroll
      for (int rg = 0; rg < 4; ++rg) {
        float z = acc[mt][nt][rg] + F.b2v[nt];
        float v = fmaxf(0.0f, fmaf(z, az[nt], dz[nt]));
        mx = fmaxf(mx, v);
      }
    mx = fmaxf(mx, __shfl_xor(mx, 16));
    mx = fmaxf(mx, __shfl_xor(mx, 32));
    pmax[nt] = mx;
  }
  if (lane < 16) {
    float* op = nf + (size_t)wid * 128;
    #pragma unroll
    for (int nt = 0; nt < 8; ++nt) op[nt * 16 + lr] = pmax[nt];
  }
}

extern "C" void kernel_launch(void* const* d_in, const int* in_sizes, int n_in,
                              void* d_out, int out_size, void* d_ws, size_t ws_size,
                              hipStream_t stream) {
  const float* xyz  = (const float*)d_in[0];
  const float* feat = (const float*)d_in[1];
  const float* w1   = (const float*)d_in[2];
  const float* b1   = (const float*)d_in[3];
  const float* g1w  = (const float*)d_in[4];
  const float* g1b  = (const float*)d_in[5];
  const float* w2   = (const float*)d_in[6];
  const float* b2   = (const float*)d_in[7];
  const float* g2w  = (const float*)d_in[8];
  const float* g2b  = (const float*)d_in[9];
  float* ws = (float*)d_ws;
  float* cent = (float*)d_out;                    // (B,M,3)
  float* nf   = (float*)d_out + BB * MM * 3;      // (B,M,128)
  const float4* pts4 = (const float4*)(ws + PTS4_OFF);
  int*   knn   = (int*)(ws + KNN_OFF);
  float* sums1 = ws + SUM1_OFF;
  float* sums2 = ws + SUM2_OFF;
  float* a1 = ws + A1_OFF; float* d1 = ws + D1_OFF;
  float* a2 = ws + A2_OFF; float* d2 = ws + D2_OFF;
  const unsigned short* w2b = (const unsigned short*)(ws + W2B_OFF);
  const unsigned short* w1b = (const unsigned short*)(ws + W1B_OFF);
  float* y1 = ws + Y1_OFF;

  hipLaunchKernelGGL(k0_init, dim3(512), dim3(256), 0, stream, xyz, w1, w2, ws);
  hipLaunchKernelGGL(fps_kernel, dim3(16), dim3(256), 0, stream, xyz, cent);
  hipLaunchKernelGGL(knn_kernel, dim3(256), dim3(512), 0, stream, pts4, cent, knn);
  hipLaunchKernelGGL(conv1_kernel, dim3(4096), dim3(256), 0, stream,
                     xyz, feat, cent, knn, w1b, b1, y1);
  hipLaunchKernelGGL(red1_kernel, dim3(512), dim3(256), 0, stream, y1, sums1);
  hipLaunchKernelGGL(coeffs_kernel, dim3(4), dim3(256), 0, stream,
                     sums1, g1w, g1b, a1, d1, 64, 2, 1.0f / 65536.0f);
  hipLaunchKernelGGL(conv2_stats_kernel, dim3(4096), dim3(256), 0, stream,
                     y1, a1, d1, w2b, b2, sums2);
  hipLaunchKernelGGL(coeffs_kernel, dim3(8), dim3(256), 0, stream,
                     sums2, g2w, g2b, a2, d2, 128, 4, 1.0f / 131072.0f);
  hipLaunchKernelGGL(final_kernel, dim3(4096), dim3(256), 0, stream,
                     y1, a1, d1, w2b, b2, a2, d2, nf);
}